// Round 8
// baseline (350.367 us; speedup 1.0000x reference)
//
#include <hip/hip_runtime.h>

typedef __bf16 bf16x8 __attribute__((ext_vector_type(8)));
typedef __bf16 bf16x4 __attribute__((ext_vector_type(4)));
typedef float  f32x4  __attribute__((ext_vector_type(4)));
typedef float  f32x16 __attribute__((ext_vector_type(16)));

#define DEVI __device__ __forceinline__

DEVI bf16x8 ld8(const __bf16* p) { return *reinterpret_cast<const bf16x8*>(p); }
DEVI f32x4 mfma16(bf16x8 a, bf16x8 b, f32x4 c) {
  return __builtin_amdgcn_mfma_f32_16x16x32_bf16(a, b, c, 0, 0, 0);
}
DEVI f32x16 mfma32(bf16x8 a, bf16x8 b, f32x16 c) {
  return __builtin_amdgcn_mfma_f32_32x32x16_bf16(a, b, c, 0, 0, 0);
}
DEVI void gl_lds16(const void* g, void* l) {
  __builtin_amdgcn_global_load_lds((__attribute__((address_space(1))) void*)g,
                                   (__attribute__((address_space(3))) void*)l, 16, 0, 0);
}
DEVI unsigned pk2(float a, float b) {
  union { __bf16 h[2]; unsigned u; } x;
  x.h[0] = (__bf16)a; x.h[1] = (__bf16)b; return x.u;
}

// ---------- x fp32 -> bf16 ----------
__global__ void k_cvt(const float* __restrict__ in, __bf16* __restrict__ out, int n4) {
  int i = blockIdx.x * blockDim.x + threadIdx.x;
  if (i >= n4) return;
  f32x4 v = reinterpret_cast<const f32x4*>(in)[i];
  bf16x4 o;
  o[0] = (__bf16)v[0]; o[1] = (__bf16)v[1]; o[2] = (__bf16)v[2]; o[3] = (__bf16)v[3];
  reinterpret_cast<bf16x4*>(out)[i] = o;
}

// ---------- transpose fp32 [R][C] -> bf16 [C][R] (optionally hi+lo split) ----------
template<bool LO>
__global__ void k_tr(const float* __restrict__ in, __bf16* __restrict__ oh,
                     __bf16* __restrict__ ol, int R, int C) {
  __shared__ float t[32][33];
  const float* im = in + (size_t)blockIdx.z * R * C;
  __bf16* ohm = oh + (size_t)blockIdx.z * R * C;
  __bf16* olm = LO ? (ol + (size_t)blockIdx.z * R * C) : nullptr;
  int c0 = blockIdx.x * 32, r0 = blockIdx.y * 32;
  int tx = threadIdx.x & 31, ty = threadIdx.x >> 5;
  #pragma unroll
  for (int k = 0; k < 32; k += 8)
    t[ty + k][tx] = im[(size_t)(r0 + ty + k) * C + c0 + tx];
  __syncthreads();
  #pragma unroll
  for (int k = 0; k < 32; k += 8) {
    float v = t[tx][ty + k];
    size_t o = (size_t)(c0 + ty + k) * R + r0 + tx;
    __bf16 h = (__bf16)v;
    ohm[o] = h;
    if (LO) olm[o] = (__bf16)(v - (float)h);
  }
}

// ---------- QKV projection ----------
__global__ __launch_bounds__(256) void k_qkv(
    const __bf16* __restrict__ xb, const __bf16* __restrict__ Wt,
    const float* __restrict__ bq, const float* __restrict__ bk, const float* __restrict__ bv,
    __bf16* __restrict__ Qb, __bf16* __restrict__ Kb, __bf16* __restrict__ Vtb) {
  const int w = threadIdx.x >> 6, lane = threadIdx.x & 63;
  const int g = lane >> 4, qc = lane & 15;
  const int which = blockIdx.z >> 3, h = blockIdx.z & 7;
  const int m0 = blockIdx.x * 64 + w * 16;
  const int n0 = blockIdx.y * 64;
  const __bf16* Wm = Wt + ((size_t)blockIdx.z << 16);
  const float* bias = (which == 0 ? bq : which == 1 ? bk : bv) + h * 256;
  f32x4 acc[4] = {};
  const __bf16* ap = xb + (m0 + qc) * 256 + g * 8;
  #pragma unroll
  for (int kk = 0; kk < 8; kk++) {
    bf16x8 af = ld8(ap + kk * 32);
    #pragma unroll
    for (int nt = 0; nt < 4; nt++) {
      bf16x8 bf = ld8(Wm + (n0 + nt * 16 + qc) * 256 + kk * 32 + g * 8);
      acc[nt] = mfma16(af, bf, acc[nt]);
    }
  }
  const int b = m0 >> 11, s0 = (m0 & 2047);
  const int bh = b * 8 + h;
  #pragma unroll
  for (int nt = 0; nt < 4; nt++) {
    const int e = n0 + nt * 16 + qc;
    const float be = bias[e];
    if (which == 2) {
      bf16x4 pk;
      #pragma unroll
      for (int r = 0; r < 4; r++) pk[r] = (__bf16)(acc[nt][r] + be);
      *reinterpret_cast<bf16x4*>(Vtb + ((bh * 256 + e) * 2048 + s0 + g * 4)) = pk;
    } else {
      // Q folds 1/sqrt(D) * log2(e)  (attention runs in exp2 domain)
      const float sc = (which == 0) ? 0.0625f * 1.4426950408889634f : 1.0f;
      __bf16* Out = (which == 0) ? Qb : Kb;
      #pragma unroll
      for (int r = 0; r < 4; r++)
        Out[(bh * 2048 + s0 + g * 4 + r) * 256 + e] = (__bf16)((acc[nt][r] + be) * sc);
    }
  }
}

// ---------- flash attention v7: kv-split x2 across blocks, fp32 partials ----------
// grid 512 blocks x 256 thr = 2 blocks/CU (VGPR ~216 uncapped + 64KB LDS).
// NO waves-per-EU hint: (256,2) caps VGPR at 128 and spills (R7 lesson).
__global__ __launch_bounds__(256) void k_attn(
    const __bf16* __restrict__ Qb, const __bf16* __restrict__ Kb,
    const __bf16* __restrict__ Vtb, float* __restrict__ Pb, float2* __restrict__ MLb) {
  __shared__ __align__(16) unsigned char smem[65536];
  const int tid = threadIdx.x;
  const int wl = tid >> 6, lane = tid & 63;
  const int hi = lane >> 5, q = lane & 31;

  const int bid = blockIdx.x;
  const int s = (bid & 7) * 64 + (bid >> 3);   // XCD-chunked: bh pair {2x,2x+1} per XCD
  const int bh = s >> 5, rem = s & 31;
  const int qt = rem >> 1, half = rem & 1;

  const int q0w = qt * 128 + wl * 32;
  const char* Kg = (const char*)Kb + ((size_t)(bh * 2048 + half * 1024)) * 512;
  const char* Vg = (const char*)Vtb + (size_t)bh * 256 * 4096 + (size_t)half * 2048;
  const __bf16* Qp = Qb + ((size_t)(bh * 2048 + q0w + q)) * 256;

  bf16x8 qf[16];
  #pragma unroll
  for (int kk = 0; kk < 16; kk++) qf[kk] = ld8(Qp + kk * 16 + hi * 8);

  f32x16 acc[8];
  #pragma unroll
  for (int i = 0; i < 8; i++)
    #pragma unroll
    for (int e = 0; e < 16; e++) acc[i][e] = 0.f;

  auto stage = [&](int nb, int t) {
    unsigned char* kbp = smem + nb * 16384 + wl * 4096;
    unsigned char* vbp = smem + 32768 + nb * 16384 + wl * 4096;
    #pragma unroll
    for (int j = 0; j < 4; j++) {
      const int O = wl * 4096 + j * 1024 + lane * 16;
      const int kv = O >> 9;
      const int c = ((O >> 4) & 31) ^ (kv & 15);
      gl_lds16(Kg + (size_t)t * 16384 + (size_t)kv * 512 + c * 16, kbp + j * 1024);
    }
    #pragma unroll
    for (int j = 0; j < 4; j++) {
      const int O = wl * 4096 + j * 1024 + lane * 16;
      const int sr = O >> 9;
      const int kvc = ((O >> 4) & 3) ^ (sr & 3);
      const int d = sr * 8 + ((O >> 6) & 7);
      gl_lds16(Vg + (size_t)d * 4096 + (size_t)t * 64 + kvc * 16, vbp + j * 1024);
    }
  };

  float m_run = -3.0e38f, l_run = 0.f;
  stage(0, 0);
  __syncthreads();

  for (int t = 0; t < 32; t++) {
    const int cur = t & 1;
    const unsigned char* kbc = smem + cur * 16384;
    const unsigned char* vbc = smem + 32768 + cur * 16384;
    if (t < 31) stage(cur ^ 1, t + 1);

    // ---- QK^T (swapped): st = S^T[kv][q], col=q ----
    f32x16 st;
    #pragma unroll
    for (int e = 0; e < 16; e++) st[e] = 0.f;
    __builtin_amdgcn_s_setprio(1);
    #pragma unroll
    for (int kk = 0; kk < 16; kk++) {
      const int off = q * 512 + ((((kk << 1) + hi) ^ (q & 15)) << 4);
      bf16x8 kf = *reinterpret_cast<const bf16x8*>(kbc + off);
      st = mfma32(kf, qf[kk], st);
    }
    __builtin_amdgcn_s_setprio(0);

    // ---- online softmax in exp2 domain, defer-max THR=8 ----
    float rmax = st[0];
    #pragma unroll
    for (int r = 1; r < 16; r++) rmax = fmaxf(rmax, st[r]);
    rmax = fmaxf(rmax, __shfl_xor(rmax, 32));
    if (__any(rmax > m_run + 8.0f)) {
      const float m_new = fmaxf(rmax, m_run);
      const float alpha = exp2f(m_run - m_new);
      m_run = m_new;
      l_run *= alpha;
      #pragma unroll
      for (int r = 0; r < 16; r++) {
        const float ar = __shfl(alpha, (r & 3) + 8 * (r >> 2) + 4 * hi);
        #pragma unroll
        for (int dt = 0; dt < 8; dt++) acc[dt][r] *= ar;
      }
    }
    float rs = 0.f;
    #pragma unroll
    for (int r = 0; r < 16; r++) { st[r] = exp2f(st[r] - m_run); rs += st[r]; }
    rs += __shfl_xor(rs, 32);
    l_run += rs;

    // ---- P -> PV A-frags fully in-register (pack + lane^32 exchange) ----
    bf16x8 pa[2];
    #pragma unroll
    for (int c = 0; c < 2; c++) {
      const unsigned L0 = pk2(st[c * 8 + 0], st[c * 8 + 1]);
      const unsigned L1 = pk2(st[c * 8 + 2], st[c * 8 + 3]);
      const unsigned H0 = pk2(st[c * 8 + 4], st[c * 8 + 5]);
      const unsigned H1 = pk2(st[c * 8 + 6], st[c * 8 + 7]);
      const unsigned xL0 = __shfl_xor(L0, 32), xL1 = __shfl_xor(L1, 32);
      const unsigned xH0 = __shfl_xor(H0, 32), xH1 = __shfl_xor(H1, 32);
      unsigned pw[4];
      pw[0] = hi ? xH0 : L0;  pw[1] = hi ? xH1 : L1;
      pw[2] = hi ? H0 : xL0;  pw[3] = hi ? H1 : xL1;
      pa[c] = *reinterpret_cast<bf16x8*>(pw);
    }

    // ---- PV: acc[dt] col=d=dt*32+q, rows=q-regs ----
    __builtin_amdgcn_s_setprio(1);
    #pragma unroll
    for (int dt = 0; dt < 8; dt++) {
      const int d = dt * 32 + q;
      const int base = (d >> 3) * 512 + (d & 7) * 64;
      #pragma unroll
      for (int c = 0; c < 2; c++) {
        const int off = base + ((((c << 1) + hi) ^ ((d >> 3) & 3)) << 4);
        bf16x8 vf = *reinterpret_cast<const bf16x8*>(vbc + off);
        acc[dt] = mfma32(pa[c], vf, acc[dt]);
      }
    }
    __builtin_amdgcn_s_setprio(0);
    __syncthreads();
  }

  // ---- epilogue: write unnormalized fp32 partial + (m,l) ----
  if (hi == 0) {
    MLb[half * 32768 + bh * 2048 + q0w + q] = make_float2(m_run, l_run);
  }
  float* Pp = Pb + ((size_t)(half * 16 + bh) * 2048 + q0w) * 256;
  #pragma unroll
  for (int dt = 0; dt < 8; dt++) {
    #pragma unroll
    for (int r = 0; r < 16; r++) {
      const int qrow = (r & 3) + 8 * (r >> 2) + 4 * hi;
      Pp[(size_t)qrow * 256 + dt * 32 + q] = acc[dt][r];
    }
  }
}

// ---------- output projection fused with kv-half merge ----------
// grid (64 m-tiles, 8 heads) x 256 thr. Each block: one head's K=256 slice,
// full n=256, merging the two fp32 partials in-register (each byte read once).
__global__ __launch_bounds__(256) void k_out(
    const float* __restrict__ P0, const float2* __restrict__ ML,
    const __bf16* __restrict__ Wh, const __bf16* __restrict__ Wl,
    const float* __restrict__ bo, float* __restrict__ out) {
  const int w = threadIdx.x >> 6, lane = threadIdx.x & 63;
  const int g = lane >> 4, qc = lane & 15;
  const int m0 = blockIdx.x * 64 + w * 16;
  const int h = blockIdx.y;
  const int m = m0 + qc, b = m >> 11, qr = m & 2047;
  const int bh = b * 8 + h;
  const float* A0 = P0 + ((size_t)bh * 2048 + qr) * 256;
  const float* A1 = A0 + (16ull * 2048 * 256);
  const float2 ml0 = ML[bh * 2048 + qr];
  const float2 ml1 = ML[32768 + bh * 2048 + qr];
  const float mt = fmaxf(ml0.x, ml1.x);
  const float a0 = exp2f(ml0.x - mt), a1 = exp2f(ml1.x - mt);
  const float inv = 1.f / (ml0.y * a0 + ml1.y * a1);
  const float s0 = a0 * inv, s1 = a1 * inv;
  f32x4 acc[16] = {};
  #pragma unroll
  for (int kk = 0; kk < 8; kk++) {
    const int dloc = kk * 32 + g * 8;
    f32x4 u0 = *reinterpret_cast<const f32x4*>(A0 + dloc);
    f32x4 u1 = *reinterpret_cast<const f32x4*>(A0 + dloc + 4);
    f32x4 v0 = *reinterpret_cast<const f32x4*>(A1 + dloc);
    f32x4 v1 = *reinterpret_cast<const f32x4*>(A1 + dloc + 4);
    bf16x8 ah, al;
    #pragma unroll
    for (int j = 0; j < 4; j++) {
      const float f0 = u0[j] * s0 + v0[j] * s1;
      const float f1 = u1[j] * s0 + v1[j] * s1;
      const __bf16 h0 = (__bf16)f0, h1 = (__bf16)f1;
      ah[j] = h0;     al[j] = (__bf16)(f0 - (float)h0);
      ah[4 + j] = h1; al[4 + j] = (__bf16)(f1 - (float)h1);
    }
    const int kglob = h * 256 + dloc;
    #pragma unroll
    for (int nt = 0; nt < 16; nt++) {
      const size_t nrow = (size_t)(nt * 16 + qc) * 2048 + kglob;
      bf16x8 wh = ld8(Wh + nrow);
      bf16x8 wlv = ld8(Wl + nrow);
      acc[nt] = mfma16(ah, wh, acc[nt]);
      acc[nt] = mfma16(al, wh, acc[nt]);
      acc[nt] = mfma16(ah, wlv, acc[nt]);
    }
  }
  #pragma unroll
  for (int nt = 0; nt < 16; nt++) {
    const int n = nt * 16 + qc;
    const float bb = (h == 0) ? bo[n] : 0.f;
    #pragma unroll
    for (int r = 0; r < 4; r++)
      unsafeAtomicAdd(&out[(m0 + g * 4 + r) * 256 + n], acc[nt][r] + bb);
  }
}

extern "C" void kernel_launch(void* const* d_in, const int* in_sizes, int n_in,
                              void* d_out, int out_size, void* d_ws, size_t ws_size,
                              hipStream_t stream) {
  const float* x  = (const float*)d_in[0];
  const float* Wq = (const float*)d_in[1];
  const float* bq = (const float*)d_in[2];
  const float* Wk = (const float*)d_in[3];
  const float* bk = (const float*)d_in[4];
  const float* Wv = (const float*)d_in[5];
  const float* bv = (const float*)d_in[6];
  const float* Wo = (const float*)d_in[7];
  const float* bo = (const float*)d_in[8];
  char* p = (char*)d_ws;
  __bf16* xb  = (__bf16*)(p);                          // 2 MB  [4096][256]
  __bf16* Wt  = (__bf16*)(p + (2ull  << 20));          // 3 MB  [3][8][256 e][256 d]
  __bf16* Woh = (__bf16*)(p + (5ull  << 20));          // 1 MB  [256 n][2048 k]
  __bf16* Wol = (__bf16*)(p + (6ull  << 20));          // 1 MB
  __bf16* Qb  = (__bf16*)(p + (7ull  << 20));          // 16 MB [bh][s][d] (scale folded)
  __bf16* Kb  = (__bf16*)(p + (23ull << 20));          // 16 MB [bh][s][d]
  __bf16* Vtb = (__bf16*)(p + (39ull << 20));          // 16 MB [bh][d][s]
  float*  Pb  = (float*)(p + (55ull << 20));           // 64 MB [2 half][bh][q][d] fp32
  float2* MLb = (float2*)(p + (119ull << 20));         // 1 MB  [2 half][bh][q] (m,l)

  k_cvt<<<dim3(1024), dim3(256), 0, stream>>>(x, xb, 262144);
  k_tr<false><<<dim3(8, 8, 8),  dim3(256), 0, stream>>>(Wq, Wt + 0 * 524288, nullptr, 256, 256);
  k_tr<false><<<dim3(8, 8, 8),  dim3(256), 0, stream>>>(Wk, Wt + 1 * 524288, nullptr, 256, 256);
  k_tr<false><<<dim3(8, 8, 8),  dim3(256), 0, stream>>>(Wv, Wt + 2 * 524288, nullptr, 256, 256);
  k_tr<true ><<<dim3(8, 64, 1), dim3(256), 0, stream>>>(Wo, Woh, Wol, 2048, 256);
  k_qkv<<<dim3(64, 4, 24), dim3(256), 0, stream>>>(xb, Wt, bq, bk, bv, Qb, Kb, Vtb);
  k_attn<<<dim3(512), dim3(256), 0, stream>>>(Qb, Kb, Vtb, Pb, MLb);
  (void)hipMemsetAsync(d_out, 0, (size_t)out_size * sizeof(float), stream);
  k_out<<<dim3(64, 8), dim3(256), 0, stream>>>(Pb, MLb, Woh, Wol, bo, (float*)d_out);
}

// Round 10
// 320.102 us; speedup vs baseline: 1.0945x; 1.0945x over previous
//
#include <hip/hip_runtime.h>

typedef __bf16 bf16x8 __attribute__((ext_vector_type(8)));
typedef __bf16 bf16x4 __attribute__((ext_vector_type(4)));
typedef float  f32x4  __attribute__((ext_vector_type(4)));
typedef float  f32x16 __attribute__((ext_vector_type(16)));

#define DEVI __device__ __forceinline__

DEVI bf16x8 ld8(const __bf16* p) { return *reinterpret_cast<const bf16x8*>(p); }
DEVI f32x4 mfma16(bf16x8 a, bf16x8 b, f32x4 c) {
  return __builtin_amdgcn_mfma_f32_16x16x32_bf16(a, b, c, 0, 0, 0);
}
DEVI f32x16 mfma32(bf16x8 a, bf16x8 b, f32x16 c) {
  return __builtin_amdgcn_mfma_f32_32x32x16_bf16(a, b, c, 0, 0, 0);
}
DEVI void gl_lds16(const void* g, void* l) {
  __builtin_amdgcn_global_load_lds((__attribute__((address_space(1))) void*)g,
                                   (__attribute__((address_space(3))) void*)l, 16, 0, 0);
}
DEVI unsigned pk2(float a, float b) {
  union { __bf16 h[2]; unsigned u; } x;
  x.h[0] = (__bf16)a; x.h[1] = (__bf16)b; return x.u;
}

#if __has_builtin(__builtin_amdgcn_exp2f)
#define EXP2(x) __builtin_amdgcn_exp2f(x)
#else
#define EXP2(x) exp2f(x)
#endif

// ---------- x fp32 -> bf16 ----------
__global__ void k_cvt(const float* __restrict__ in, __bf16* __restrict__ out, int n4) {
  int i = blockIdx.x * blockDim.x + threadIdx.x;
  if (i >= n4) return;
  f32x4 v = reinterpret_cast<const f32x4*>(in)[i];
  bf16x4 o;
  o[0] = (__bf16)v[0]; o[1] = (__bf16)v[1]; o[2] = (__bf16)v[2]; o[3] = (__bf16)v[3];
  reinterpret_cast<bf16x4*>(out)[i] = o;
}

// ---------- transpose fp32 [R][C] -> bf16 [C][R] (optionally hi+lo split) ----------
template<bool LO>
__global__ void k_tr(const float* __restrict__ in, __bf16* __restrict__ oh,
                     __bf16* __restrict__ ol, int R, int C) {
  __shared__ float t[32][33];
  const float* im = in + (size_t)blockIdx.z * R * C;
  __bf16* ohm = oh + (size_t)blockIdx.z * R * C;
  __bf16* olm = LO ? (ol + (size_t)blockIdx.z * R * C) : nullptr;
  int c0 = blockIdx.x * 32, r0 = blockIdx.y * 32;
  int tx = threadIdx.x & 31, ty = threadIdx.x >> 5;
  #pragma unroll
  for (int k = 0; k < 32; k += 8)
    t[ty + k][tx] = im[(size_t)(r0 + ty + k) * C + c0 + tx];
  __syncthreads();
  #pragma unroll
  for (int k = 0; k < 32; k += 8) {
    float v = t[tx][ty + k];
    size_t o = (size_t)(c0 + ty + k) * R + r0 + tx;
    __bf16 h = (__bf16)v;
    ohm[o] = h;
    if (LO) olm[o] = (__bf16)(v - (float)h);
  }
}

// ---------- QKV projection ----------
__global__ __launch_bounds__(256) void k_qkv(
    const __bf16* __restrict__ xb, const __bf16* __restrict__ Wt,
    const float* __restrict__ bq, const float* __restrict__ bk, const float* __restrict__ bv,
    __bf16* __restrict__ Qb, __bf16* __restrict__ Kb, __bf16* __restrict__ Vtb) {
  const int w = threadIdx.x >> 6, lane = threadIdx.x & 63;
  const int g = lane >> 4, qc = lane & 15;
  const int which = blockIdx.z >> 3, h = blockIdx.z & 7;
  const int m0 = blockIdx.x * 64 + w * 16;
  const int n0 = blockIdx.y * 64;
  const __bf16* Wm = Wt + ((size_t)blockIdx.z << 16);
  const float* bias = (which == 0 ? bq : which == 1 ? bk : bv) + h * 256;
  f32x4 acc[4] = {};
  const __bf16* ap = xb + (m0 + qc) * 256 + g * 8;
  #pragma unroll
  for (int kk = 0; kk < 8; kk++) {
    bf16x8 af = ld8(ap + kk * 32);
    #pragma unroll
    for (int nt = 0; nt < 4; nt++) {
      bf16x8 bf = ld8(Wm + (n0 + nt * 16 + qc) * 256 + kk * 32 + g * 8);
      acc[nt] = mfma16(af, bf, acc[nt]);
    }
  }
  const int b = m0 >> 11, s0 = (m0 & 2047);
  const int bh = b * 8 + h;
  #pragma unroll
  for (int nt = 0; nt < 4; nt++) {
    const int e = n0 + nt * 16 + qc;
    const float be = bias[e];
    if (which == 2) {
      bf16x4 pk;
      #pragma unroll
      for (int r = 0; r < 4; r++) pk[r] = (__bf16)(acc[nt][r] + be);
      *reinterpret_cast<bf16x4*>(Vtb + ((bh * 256 + e) * 2048 + s0 + g * 4)) = pk;
    } else {
      // Q folds 1/sqrt(D) * log2(e)  (attention runs in exp2 domain)
      const float sc = (which == 0) ? 0.0625f * 1.4426950408889634f : 1.0f;
      __bf16* Out = (which == 0) ? Qb : Kb;
      #pragma unroll
      for (int r = 0; r < 4; r++)
        Out[(bh * 2048 + s0 + g * 4 + r) * 256 + e] = (__bf16)((acc[nt][r] + be) * sc);
    }
  }
}

// ---------- flash attention v9: KVBLK=64 structure (R9) with R7-proven shfl_xor ----------
// grid 256 blocks x 256 thr (16bh x 16qt), full kv per block, 32 double-buffered
// 64-kv tiles, 128KB LDS (1 block/CU; VGPRs up to ~450 free). Two independent
// 16-MFMA QK chains; ONE barrier + ONE cross-half reduce pair per 64 kv.
// All lane exchanges via __shfl_xor(.,32) — permlane asm was the R9 bug.
__global__ __launch_bounds__(256) void k_attn(
    const __bf16* __restrict__ Qb, const __bf16* __restrict__ Kb,
    const __bf16* __restrict__ Vtb, __bf16* __restrict__ Oh, __bf16* __restrict__ Ol) {
  __shared__ __align__(16) unsigned char smem[131072];
  const int tid = threadIdx.x;
  const int wl = tid >> 6, lane = tid & 63;
  const int hi = lane >> 5, q = lane & 31;

  const int bid = blockIdx.x;
  const int s = (bid & 7) * 32 + (bid >> 3);      // XCD-chunked swizzle (bijective)
  const int bh = s >> 4, qt = s & 15;

  const int q0w = qt * 128 + wl * 32;
  const char* Kg = (const char*)Kb + ((size_t)bh * 2048) * 512;
  const char* Vg = (const char*)Vtb + (size_t)bh * 256 * 4096;
  const __bf16* Qp = Qb + ((size_t)(bh * 2048 + q0w + q)) * 256;

  bf16x8 qf[16];
  #pragma unroll
  for (int kk = 0; kk < 16; kk++) qf[kk] = ld8(Qp + kk * 16 + hi * 8);

  f32x16 acc[8];
  #pragma unroll
  for (int i = 0; i < 8; i++)
    #pragma unroll
    for (int e = 0; e < 16; e++) acc[i][e] = 0.f;

  // stage one 64-kv tile: K 32KB ([64 kv][512B], 4-bit XOR swz) +
  // V 32KB ([32 super-rows of 8 d-rows x 128B][8 kv-chunks], 3-bit XOR swz)
  auto stage = [&](int nb, int t) {
    unsigned char* kbp = smem + nb * 32768 + wl * 8192;
    unsigned char* vbp = smem + 65536 + nb * 32768 + wl * 8192;
    #pragma unroll
    for (int j = 0; j < 8; j++) {
      const int O = wl * 8192 + j * 1024 + lane * 16;
      const int kv = O >> 9;
      const int c = ((O >> 4) & 31) ^ (kv & 15);
      gl_lds16(Kg + (size_t)t * 32768 + (size_t)kv * 512 + c * 16, kbp + j * 1024);
    }
    #pragma unroll
    for (int j = 0; j < 8; j++) {
      const int O = wl * 8192 + j * 1024 + lane * 16;
      const int sr = O >> 10;
      const int ch = ((O >> 4) & 7) ^ (sr & 7);
      const int d = sr * 8 + ((O >> 7) & 7);
      gl_lds16(Vg + (size_t)d * 4096 + (size_t)t * 128 + ch * 16, vbp + j * 1024);
    }
  };

  float m_run = -3.0e38f, l_run = 0.f;
  stage(0, 0);
  __syncthreads();

  for (int t = 0; t < 32; t++) {
    const int cur = t & 1;
    const unsigned char* kbc = smem + cur * 32768;
    const unsigned char* vbc = smem + 65536 + cur * 32768;
    if (t < 31) stage(cur ^ 1, t + 1);

    // ---- QK^T (swapped): two independent 16-MFMA chains (kv rows q, 32+q) ----
    f32x16 st0, st1;
    #pragma unroll
    for (int e = 0; e < 16; e++) { st0[e] = 0.f; st1[e] = 0.f; }
    __builtin_amdgcn_s_setprio(1);
    #pragma unroll
    for (int kk = 0; kk < 16; kk++) {
      const int o0 = q * 512 + ((((kk << 1) + hi) ^ (q & 15)) << 4);
      bf16x8 k0 = *reinterpret_cast<const bf16x8*>(kbc + o0);
      bf16x8 k1 = *reinterpret_cast<const bf16x8*>(kbc + o0 + 16384);
      st0 = mfma32(k0, qf[kk], st0);
      st1 = mfma32(k1, qf[kk], st1);
    }
    __builtin_amdgcn_s_setprio(0);

    // ---- online softmax over 64 values, exp2 domain, defer-max THR=8 ----
    f32x16 mx;
    #pragma unroll
    for (int r = 0; r < 16; r++) mx[r] = fmaxf(st0[r], st1[r]);
    #pragma unroll
    for (int w2 = 8; w2 > 0; w2 >>= 1)
      #pragma unroll
      for (int r = 0; r < w2; r++) mx[r] = fmaxf(mx[r], mx[r + w2]);
    const float rmax = fmaxf(mx[0], __shfl_xor(mx[0], 32));
    if (__any(rmax > m_run + 8.0f)) {
      const float m_new = fmaxf(rmax, m_run);
      const float alpha = EXP2(m_run - m_new);
      m_run = m_new;
      l_run *= alpha;
      #pragma unroll
      for (int r = 0; r < 16; r++) {
        const float ar = __shfl(alpha, (r & 3) + 8 * (r >> 2) + 4 * hi);
        #pragma unroll
        for (int dt = 0; dt < 8; dt++) acc[dt][r] *= ar;
      }
    }
    f32x16 sm_;
    #pragma unroll
    for (int r = 0; r < 16; r++) {
      st0[r] = EXP2(st0[r] - m_run);
      st1[r] = EXP2(st1[r] - m_run);
      sm_[r] = st0[r] + st1[r];
    }
    #pragma unroll
    for (int w2 = 8; w2 > 0; w2 >>= 1)
      #pragma unroll
      for (int r = 0; r < w2; r++) sm_[r] += sm_[r + w2];
    l_run += sm_[0] + __shfl_xor(sm_[0], 32);

    // ---- P -> 4 PV A-frags in-register (pk2 + shfl_xor exchange, R7-proven) ----
    bf16x8 pa[4];
    #define MKCHUNK(STV, H2, OUT) {                          \
      const unsigned L0 = pk2(STV[H2 * 8 + 0], STV[H2 * 8 + 1]);  \
      const unsigned L1 = pk2(STV[H2 * 8 + 2], STV[H2 * 8 + 3]);  \
      const unsigned H0 = pk2(STV[H2 * 8 + 4], STV[H2 * 8 + 5]);  \
      const unsigned H1 = pk2(STV[H2 * 8 + 6], STV[H2 * 8 + 7]);  \
      const unsigned xL0 = __shfl_xor(L0, 32), xL1 = __shfl_xor(L1, 32); \
      const unsigned xH0 = __shfl_xor(H0, 32), xH1 = __shfl_xor(H1, 32); \
      unsigned pw[4];                                        \
      pw[0] = hi ? xH0 : L0;  pw[1] = hi ? xH1 : L1;         \
      pw[2] = hi ? H0 : xL0;  pw[3] = hi ? H1 : xL1;         \
      OUT = *reinterpret_cast<bf16x8*>(pw); }
    MKCHUNK(st0, 0, pa[0]); MKCHUNK(st0, 1, pa[1]);
    MKCHUNK(st1, 0, pa[2]); MKCHUNK(st1, 1, pa[3]);
    #undef MKCHUNK

    // ---- PV: acc[dt] col=d=dt*32+q ----
    __builtin_amdgcn_s_setprio(1);
    #pragma unroll
    for (int dt = 0; dt < 8; dt++) {
      const int d = dt * 32 + q;
      const int base = (d >> 3) * 1024 + (d & 7) * 128;
      const int key = (d >> 3) & 7;
      #pragma unroll
      for (int c = 0; c < 4; c++) {
        const int off = base + ((((c << 1) + hi) ^ key) << 4);
        bf16x8 vf = *reinterpret_cast<const bf16x8*>(vbc + off);
        acc[dt] = mfma32(pa[c], vf, acc[dt]);
      }
    }
    __builtin_amdgcn_s_setprio(0);
    __syncthreads();
  }

  // ---- epilogue: divide by l, split hi/lo bf16 ----
  float linv[16];
  #pragma unroll
  for (int r = 0; r < 16; r++)
    linv[r] = 1.f / __shfl(l_run, (r & 3) + 8 * (r >> 2) + 4 * hi);
  const int b = bh >> 3, h = bh & 7;
  #pragma unroll
  for (int dt = 0; dt < 8; dt++) {
    #pragma unroll
    for (int r = 0; r < 16; r++) {
      const float v = acc[dt][r] * linv[r];
      const int qrow = (r & 3) + 8 * (r >> 2) + 4 * hi;
      const size_t off = (size_t)b * (2048 * 2048) +
                         (size_t)(q0w + qrow) * 2048 + h * 256 + dt * 32 + q;
      const __bf16 hv = (__bf16)v;
      Oh[off] = hv;
      Ol[off] = (__bf16)(v - (float)hv);
    }
  }
}

// ---------- output projection, K-split x2 + atomic accumulate ----------
__global__ __launch_bounds__(256) void k_out(
    const __bf16* __restrict__ Oh, const __bf16* __restrict__ Ol,
    const __bf16* __restrict__ Wh, const __bf16* __restrict__ Wl,
    const float* __restrict__ bo, float* __restrict__ out) {
  const int w = threadIdx.x >> 6, lane = threadIdx.x & 63;
  const int g = lane >> 4, qc = lane & 15;
  const int m0 = blockIdx.x * 64 + w * 16, n0 = blockIdx.y * 64;
  const int k0 = blockIdx.z * 1024;
  f32x4 acc[4] = {};
  const __bf16* ah_p = Oh + (size_t)(m0 + qc) * 2048 + k0 + g * 8;
  const __bf16* al_p = Ol + (size_t)(m0 + qc) * 2048 + k0 + g * 8;
  for (int kk = 0; kk < 32; kk++) {
    bf16x8 ah = ld8(ah_p + kk * 32);
    bf16x8 al = ld8(al_p + kk * 32);
    #pragma unroll
    for (int nt = 0; nt < 4; nt++) {
      const size_t nrow = (size_t)(n0 + nt * 16 + qc) * 2048 + k0 + kk * 32 + g * 8;
      bf16x8 bh = ld8(Wh + nrow);
      bf16x8 bl = ld8(Wl + nrow);
      acc[nt] = mfma16(ah, bh, acc[nt]);
      acc[nt] = mfma16(al, bh, acc[nt]);
      acc[nt] = mfma16(ah, bl, acc[nt]);
    }
  }
  #pragma unroll
  for (int nt = 0; nt < 4; nt++) {
    const int n = n0 + nt * 16 + qc;
    const float bb = (blockIdx.z == 0) ? bo[n] : 0.f;
    #pragma unroll
    for (int r = 0; r < 4; r++)
      unsafeAtomicAdd(&out[(m0 + g * 4 + r) * 256 + n], acc[nt][r] + bb);
  }
}

extern "C" void kernel_launch(void* const* d_in, const int* in_sizes, int n_in,
                              void* d_out, int out_size, void* d_ws, size_t ws_size,
                              hipStream_t stream) {
  const float* x  = (const float*)d_in[0];
  const float* Wq = (const float*)d_in[1];
  const float* bq = (const float*)d_in[2];
  const float* Wk = (const float*)d_in[3];
  const float* bk = (const float*)d_in[4];
  const float* Wv = (const float*)d_in[5];
  const float* bv = (const float*)d_in[6];
  const float* Wo = (const float*)d_in[7];
  const float* bo = (const float*)d_in[8];
  char* p = (char*)d_ws;
  __bf16* xb  = (__bf16*)(p);                          // 2 MB  [4096][256]
  __bf16* Wt  = (__bf16*)(p + (2ull  << 20));          // 3 MB  [3][8][256 e][256 d]
  __bf16* Woh = (__bf16*)(p + (5ull  << 20));          // 1 MB  [256 n][2048 k]
  __bf16* Wol = (__bf16*)(p + (6ull  << 20));          // 1 MB
  __bf16* Qb  = (__bf16*)(p + (7ull  << 20));          // 16 MB [bh][s][d] (scale folded)
  __bf16* Kb  = (__bf16*)(p + (23ull << 20));          // 16 MB [bh][s][d]
  __bf16* Vtb = (__bf16*)(p + (39ull << 20));          // 16 MB [bh][d][s]
  __bf16* Ohb = (__bf16*)(p + (55ull << 20));          // 16 MB [bs][h*d] hi
  __bf16* Olb = (__bf16*)(p + (71ull << 20));          // 16 MB [bs][h*d] lo

  k_cvt<<<dim3(1024), dim3(256), 0, stream>>>(x, xb, 262144);
  k_tr<false><<<dim3(8, 8, 8),  dim3(256), 0, stream>>>(Wq, Wt + 0 * 524288, nullptr, 256, 256);
  k_tr<false><<<dim3(8, 8, 8),  dim3(256), 0, stream>>>(Wk, Wt + 1 * 524288, nullptr, 256, 256);
  k_tr<false><<<dim3(8, 8, 8),  dim3(256), 0, stream>>>(Wv, Wt + 2 * 524288, nullptr, 256, 256);
  k_tr<true ><<<dim3(8, 64, 1), dim3(256), 0, stream>>>(Wo, Woh, Wol, 2048, 256);
  k_qkv<<<dim3(64, 4, 24), dim3(256), 0, stream>>>(xb, Wt, bq, bk, bv, Qb, Kb, Vtb);
  k_attn<<<dim3(256), dim3(256), 0, stream>>>(Qb, Kb, Vtb, Ohb, Olb);
  (void)hipMemsetAsync(d_out, 0, (size_t)out_size * sizeof(float), stream);
  k_out<<<dim3(64, 4, 2), dim3(256), 0, stream>>>(Ohb, Olb, Woh, Wol, bo, (float*)d_out);
}